// Round 14
// baseline (386.977 us; speedup 1.0000x reference)
//
#include <hip/hip_runtime.h>
#include <math.h>

#define TSEQ 1024
#define NH 16
#define HD 64

typedef short bf16x8 __attribute__((ext_vector_type(8)));
typedef float f32x4  __attribute__((ext_vector_type(4)));
typedef unsigned short ushort_t;
typedef unsigned long long ull_t;

__device__ __forceinline__ int lane_rank(unsigned long long m) {
  return __builtin_amdgcn_mbcnt_hi((unsigned)(m >> 32),
         __builtin_amdgcn_mbcnt_lo((unsigned)m, 0u));
}

// async global->LDS, 16B per lane; LDS dest must be wave-uniform base + lane*16
__device__ __forceinline__ void async_ld16(const ushort_t* gsrc, ushort_t* ldst) {
  __builtin_amdgcn_global_load_lds(
      (const __attribute__((address_space(1))) unsigned int*)gsrc,
      (__attribute__((address_space(3))) unsigned int*)ldst,
      16, 0, 0);
}

// ---------------- fp32 -> (hi, mid) bf16 split --------------------------------
__device__ __forceinline__ unsigned short rne_bf16(float a) {
  unsigned u = __float_as_uint(a);
  return (unsigned short)((u + 0x7fffu + ((u >> 16) & 1u)) >> 16);
}
__device__ __forceinline__ void split2(float a, unsigned short& h, unsigned short& m) {
  h = rne_bf16(a);
  float hf = __uint_as_float(((unsigned)h) << 16);
  m = rne_bf16(a - hf);
}

// fused conversion of x (4M) + wq/wk/wv/wo (1M each) into split buffers
__global__ __launch_bounds__(256) void conv_split(
    const float* __restrict__ x,
    const float* __restrict__ wq, const float* __restrict__ wk,
    const float* __restrict__ wv, const float* __restrict__ wo,
    ushort_t* __restrict__ xs, ushort_t* __restrict__ wsb)
{
  const int e = (blockIdx.x * 256 + threadIdx.x) * 4;
  const float* src; ushort_t *hp, *mp; int off;
  if (e < (1 << 22)) {
    src = x; off = e; hp = xs; mp = xs + (1u << 22);
  } else {
    int j = e - (1 << 22);
    int mat = j >> 20; off = j & ((1 << 20) - 1);
    src = (mat == 0) ? wq : (mat == 1) ? wk : (mat == 2) ? wv : wo;
    hp = wsb + (size_t)mat * (2u << 20); mp = hp + (1u << 20);
  }
  float4 v = *(const float4*)(src + off);
  ushort4 h, m;
  split2(v.x, h.x, m.x); split2(v.y, h.y, m.y);
  split2(v.z, h.z, m.z); split2(v.w, h.w, m.w);
  *(ushort4*)(hp + off) = h;
  *(ushort4*)(mp + off) = m;
}

// ---------------- split-bf16 MFMA GEMM: C = A[M,K] * B[N,K]^T -----------------
// 3-term split: hh + hm + mh (mm dropped: |am*bm| ~ 1.6e-5 relative).
// 64x128 block tile (24KB LDS) -> 6 blocks/CU for QKV: hides the per-iter
// global_load_lds HBM drain with TLP (R13 was 3 blocks/CU, 28% occupancy).
// Per-output MFMA chain is k-ascending, identical to the 128-row version ->
// bitwise-identical C.
// mode 0: dense C store (WO).
// mode 1: in-register top-4 |v| sparsify per (row,head)-vector, dense C store.
// mode 2: sparsify + store transposed into KT[bh][j][t] (K path).
__device__ __forceinline__ void mfma_gemm_core(
    const ushort_t* __restrict__ Ah, const ushort_t* __restrict__ Am,
    const ushort_t* __restrict__ Bh, const ushort_t* __restrict__ Bm,
    float* __restrict__ C, float* __restrict__ KTb,
    const int bm, const int bn, const int mode)
{
  __shared__ ushort_t ldsA[4096];   // [split][64][32]
  __shared__ ushort_t ldsB[8192];   // [split][128][32]
  const int tid  = threadIdx.x;
  const int lane = tid & 63;
  const int w    = tid >> 6;
  const int wm = (w >> 1) << 5;     // 0 or 32
  const int wn = (w & 1) << 6;      // 0 or 64
  const int r16 = lane & 15;
  const int q   = lane >> 4;

  // per-lane global srcs; LDS dst = wave-uniform base + lane*16B (8 ushorts)
  const ushort_t* ga[2]; int dstA[2];
#pragma unroll
  for (int r = 0; r < 2; ++r) {
    const int linear = tid + 256 * r;      // [0,512)
    const int s   = linear >> 8;
    const int idx = linear & 255;
    const int row = idx >> 2;
    const int kq  = (idx & 3) << 3;
    ga[r] = (s ? Am : Ah) + (size_t)(bm + row) * 1024 + kq;
    dstA[r] = linear << 3;
  }
  const ushort_t* gb[4]; int dstB[4];
#pragma unroll
  for (int r = 0; r < 4; ++r) {
    const int linear = tid + 256 * r;      // [0,1024)
    const int s   = linear >> 9;
    const int idx = linear & 511;
    const int row = idx >> 2;
    const int kq  = (idx & 3) << 3;
    gb[r] = (s ? Bm : Bh) + (size_t)(bn + row) * 1024 + kq;
    dstB[r] = linear << 3;
  }

  f32x4 acc[2][4];
#pragma unroll
  for (int mt = 0; mt < 2; ++mt)
#pragma unroll
    for (int nt = 0; nt < 4; ++nt) { f32x4 z = {0.f, 0.f, 0.f, 0.f}; acc[mt][nt] = z; }

  for (int k0 = 0; k0 < 1024; k0 += 32) {
    __syncthreads();                 // previous iter's LDS reads complete
#pragma unroll
    for (int r = 0; r < 2; ++r) { async_ld16(ga[r], &ldsA[dstA[r]]); ga[r] += 32; }
#pragma unroll
    for (int r = 0; r < 4; ++r) { async_ld16(gb[r], &ldsB[dstB[r]]); gb[r] += 32; }
    __syncthreads();                 // implicit vmcnt(0) drains the DMA

    bf16x8 bf[4][2];
#pragma unroll
    for (int nt = 0; nt < 4; ++nt) {
      bf[nt][0] = *(const bf16x8*)&ldsB[(wn + nt * 16 + r16) * 32 + q * 8];
      bf[nt][1] = *(const bf16x8*)&ldsB[4096 + (wn + nt * 16 + r16) * 32 + q * 8];
    }
#pragma unroll
    for (int mt = 0; mt < 2; ++mt) {
      const bf16x8 ah = *(const bf16x8*)&ldsA[(wm + mt * 16 + r16) * 32 + q * 8];
      const bf16x8 am = *(const bf16x8*)&ldsA[2048 + (wm + mt * 16 + r16) * 32 + q * 8];
#pragma unroll
      for (int nt = 0; nt < 4; ++nt) {
        f32x4 c = acc[mt][nt];
        c = __builtin_amdgcn_mfma_f32_16x16x32_bf16(am, bf[nt][0], c, 0, 0, 0); // mh
        c = __builtin_amdgcn_mfma_f32_16x16x32_bf16(ah, bf[nt][1], c, 0, 0, 0); // hm
        c = __builtin_amdgcn_mfma_f32_16x16x32_bf16(ah, bf[nt][0], c, 0, 0, 0); // hh
        acc[mt][nt] = c;
      }
    }
  }

  if (mode != 0) {
    // in-register top-4 |v| sparsify: tie -> lowest j (matches jax top_k).
#pragma unroll
    for (int it = 0; it < 8; ++it) {
      const int mti = it >> 2, r4i = it & 3;
      int cons = 0;
#pragma unroll
      for (int rnd = 0; rnd < 4; ++rnd) {
        float bv = -1.0f; int bj = 1024;
#pragma unroll
        for (int nt = 0; nt < 4; ++nt) {
          const float av = ((cons >> nt) & 1) ? -1.0f : fabsf(acc[mti][nt][r4i]);
          const int jj = nt * 16 + r16;
          if (av > bv) { bv = av; bj = jj; }
        }
#pragma unroll
        for (int off = 1; off < 16; off <<= 1) {
          const float ov = __shfl_xor(bv, off);
          const int   oj = __shfl_xor(bj, off);
          if (ov > bv || (ov == bv && oj < bj)) { bv = ov; bj = oj; }
        }
        if ((bj & 15) == r16) cons |= 1 << (bj >> 4);
      }
#pragma unroll
      for (int nt = 0; nt < 4; ++nt)
        if (!((cons >> nt) & 1)) acc[mti][nt][r4i] = 0.0f;
    }
  }

  if (mode == 2) {
    // K path: store transposed into KT[bh][j][t]; acc regs are 4 consecutive t
    const int row0 = bm + wm;
    const int b = row0 >> 10;
    const int h = (bn + wn) >> 6;
    float* kb = KTb + ((size_t)(b * 16 + h) << 16);
    const int tb = (row0 & 1023) + q * 4;
#pragma unroll
    for (int mt = 0; mt < 2; ++mt) {
      const int t0 = tb + mt * 16;
#pragma unroll
      for (int nt = 0; nt < 4; ++nt) {
        const int j = nt * 16 + r16;
        *(float4*)(kb + (size_t)j * 1024 + t0) =
            make_float4(acc[mt][nt][0], acc[mt][nt][1], acc[mt][nt][2], acc[mt][nt][3]);
      }
    }
  } else {
#pragma unroll
    for (int mt = 0; mt < 2; ++mt)
#pragma unroll
      for (int nt = 0; nt < 4; ++nt)
#pragma unroll
        for (int r4 = 0; r4 < 4; ++r4)
          C[(size_t)(bm + wm + mt * 16 + q * 4 + r4) * 1024 + (bn + wn + nt * 16 + r16)] =
              acc[mt][nt][r4];
  }
}

// fused Q/K/V + sparsify + K-transpose: grid (24, 64) = 1536 blocks = 6/CU
__global__ __launch_bounds__(256, 6) void mfma_qkv(
    const ushort_t* __restrict__ xs, const ushort_t* __restrict__ wsb,
    float* __restrict__ qy, float* __restrict__ kt, float* __restrict__ vy)
{
  const int nb = blockIdx.x;
  const int which = nb >> 3;
  float* C = (which == 0) ? qy : vy;       // unused for K (mode 2)
  const int mode = (which == 1) ? 2 : 1;
  const ushort_t* Bh = wsb + (size_t)which * (2u << 20);
  mfma_gemm_core(xs, xs + (1u << 22), Bh, Bh + (1u << 20), C, kt,
                 blockIdx.y * 64, (nb & 7) * 128, mode);
}

// WO: grid (8, 64) = 512 blocks = 2/CU
__global__ __launch_bounds__(256, 2) void mfma_wo(
    const ushort_t* __restrict__ oys, const ushort_t* __restrict__ wsb,
    float* __restrict__ out)
{
  const ushort_t* Bh = wsb + (size_t)3 * (2u << 20);
  mfma_gemm_core(oys, oys + (1u << 22), Bh, Bh + (1u << 20), out, nullptr,
                 blockIdx.y * 64, blockIdx.x * 128, 0);
}

// ---------------- attention: wave-synchronous, one wave per q-row -----------
__device__ __forceinline__ unsigned mono_key(float f) {
  unsigned b = __float_as_uint(f);
  return (b & 0x80000000u) ? ~b : (b | 0x80000000u);
}

// Wave-local exact rank-select over index-ordered ps[0..cnt) (hi32 = mono
// score, lo32 = k). Selects hi32 > threshold plus first `rem` (array order)
// == threshold; writes packed (expf(s-m), k*1024) at obase into spk.
// Early exit when the boundary bin holds exactly `rem` keys.
__device__ __forceinline__ void wave_radix_sel(
    unsigned long long* ps, int cnt, int target,
    int* hr, unsigned long long* spk, int obase, bool neg, float m,
    int lane)
{
  unsigned pref = 0u; int rem = target; int sstop = 0;
  for (int pass = 0; pass < 4; ++pass) {
    const int shift = 24 - 8 * pass;
    sstop = shift;
    hr[lane] = 0; hr[lane + 64] = 0; hr[lane + 128] = 0; hr[lane + 192] = 0;
    for (int c0 = 0; c0 < cnt; c0 += 64) {
      const int t = c0 + lane;
      bool pt = (t < cnt);
      const unsigned u = pt ? (unsigned)(ps[t] >> 32) : 0u;
      if (pass > 0) pt = pt && ((u >> (shift + 8)) == (pref >> (shift + 8)));
      if (pt) atomicAdd(&hr[(u >> shift) & 255u], 1);
    }
    const int d0 = lane << 2;
    const int c0b = hr[d0], c1b = hr[d0 + 1], c2b = hr[d0 + 2], c3b = hr[d0 + 3];
    const int sum = c0b + c1b + c2b + c3b;
    int S = sum;
#pragma unroll
    for (int off = 1; off < 64; off <<= 1) {
      int t = __shfl_down(S, off);
      if (lane + off < 64) S += t;
    }
    const int above = S - sum;            // keys with digit in higher lanes
    const int cg3 = above;
    const int cg2 = above + c3b;
    const int cg1 = cg2 + c2b;
    const int cg0 = cg1 + c1b;
    const bool f0 = (cg0 < rem && rem <= cg0 + c0b);
    const bool f1 = (cg1 < rem && rem <= cg1 + c1b);
    const bool f2 = (cg2 < rem && rem <= cg2 + c2b);
    const bool f3 = (cg3 < rem && rem <= cg3 + c3b);
    const int fd  = f0 ? d0 : f1 ? (d0 + 1) : f2 ? (d0 + 2) : (d0 + 3);
    const int fcg = f0 ? cg0 : f1 ? cg1 : f2 ? cg2 : cg3;
    const int fcn = f0 ? c0b : f1 ? c1b : f2 ? c2b : c3b;
    unsigned long long fm = __ballot(f0 || f1 || f2 || f3);
    const int src = __ffsll(fm) - 1;
    const int nprefl = (int)(pref | ((unsigned)fd << shift));
    const int nreml = rem - fcg;
    const int done  = (fcn == nreml) ? 1 : 0;
    pref = (unsigned)__shfl(nprefl, src);
    rem  = __shfl(nreml, src);
    if (__shfl(done, src)) break;   // bin == rem: all members selected, exact
  }
  const unsigned phi = pref >> sstop;
  int eqbase = 0, wbase = 0;
  for (int c0 = 0; c0 < cnt; c0 += 64) {
    const int t = c0 + lane;
    const bool valt = (t < cnt);
    const unsigned long long kk = valt ? ps[t] : 0ull;
    const unsigned u = (unsigned)(kk >> 32);
    const unsigned upre = u >> sstop;
    const bool eq = valt && (upre == phi);
    unsigned long long em = __ballot(eq);
    const int eqrank = eqbase + lane_rank(em);
    const bool sf = valt && ((upre > phi) || (eq && eqrank < rem));
    unsigned long long sm = __ballot(sf);
    if (sf) {
      const int pos = wbase + lane_rank(sm);
      const float sv = neg ? __uint_as_float(~u) : __uint_as_float(u & 0x7fffffffu);
      spk[obase + pos] = ((unsigned long long)__float_as_uint(__expf(sv - m)) << 32)
                       | (unsigned)(((unsigned)kk) << 10);
    }
    eqbase += (int)__popcll(em);
    wbase  += (int)__popcll(sm);
  }
}

__global__ __launch_bounds__(256) void attn_sparse(
    const float* __restrict__ Qy, const float* __restrict__ KT,
    const float* __restrict__ Vy,
    ushort_t* __restrict__ Oh, ushort_t* __restrict__ Om)
{
  const int bh = blockIdx.y;
  const int b  = bh >> 4;
  const int h  = bh & 15;
  const int tid  = threadIdx.x;
  const int lane = tid & 63;
  const int w    = tid >> 6;
  const int bi   = blockIdx.x;
  // load-balanced row map: per-block total nvalid is constant (2050)
  const int q = (w == 0) ? bi : (w == 1) ? (511 - bi) : (w == 2) ? (512 + bi) : (1023 - bi);

  __shared__ unsigned long long pseg[4][256];
  __shared__ int   zseg[4][64];
  __shared__ unsigned long long selpk[4][64];   // packed (p:f32 hi | k*1024 lo)
  __shared__ int   hist[4][256];

  // q nonzeros: ffsll-peel the ballot mask, broadcast values via shfl
  const float qv = Qy[((size_t)(b * TSEQ + q)) * 1024 + h * HD + lane];
  unsigned long long mk = __ballot(qv != 0.0f);
  const int nnz = (int)__popcll(mk);
  unsigned long long mr = mk;
  int i0 = __ffsll(mr) - 1; if (i0 < 0) i0 = 0; mr &= mr - 1;
  int i1 = __ffsll(mr) - 1; if (i1 < 0) i1 = 0; mr &= mr - 1;
  int i2 = __ffsll(mr) - 1; if (i2 < 0) i2 = 0; mr &= mr - 1;
  int i3 = __ffsll(mr) - 1; if (i3 < 0) i3 = 0;
  float v0 = __shfl(qv, i0); if (nnz < 1) v0 = 0.0f;
  float v1 = __shfl(qv, i1); if (nnz < 2) v1 = 0.0f;
  float v2 = __shfl(qv, i2); if (nnz < 3) v2 = 0.0f;
  float v3 = __shfl(qv, i3); if (nnz < 4) v3 = 0.0f;
  const float* ktb = KT + (size_t)bh * HD * TSEQ;
  const float* kr0 = ktb + (size_t)i0 * TSEQ;
  const float* kr1 = ktb + (size_t)i1 * TSEQ;
  const float* kr2 = ktb + (size_t)i2 * TSEQ;
  const float* kr3 = ktb + (size_t)i3 * TSEQ;

  const int nvalid = q + 1;
  int nsel;

  if (nvalid <= 64) {
    const bool val = (lane < nvalid);
    float s = (v0 * kr0[lane] + v1 * kr1[lane] + v2 * kr2[lane] + v3 * kr3[lane]) * 0.125f;
    float mloc = val ? s : -INFINITY;
#pragma unroll
    for (int off = 32; off; off >>= 1) mloc = fmaxf(mloc, __shfl_xor(mloc, off));
    if (val)
      selpk[w][lane] = ((unsigned long long)__float_as_uint(__expf(s - mloc)) << 32)
                     | (unsigned)(lane << 10);
    nsel = nvalid;
  } else {
    int cp = 0, cz = 0;
    float mloc = -INFINITY;
#pragma unroll 2
    for (int k0 = 0; k0 < nvalid; k0 += 64) {
      const int k = k0 + lane;
      const bool val = (k < nvalid);
      // unguarded loads: worst-case 63 elements past row end stay inside d_ws
      float s = (v0 * kr0[k] + v1 * kr1[k] + v2 * kr2[k] + v3 * kr3[k]) * 0.125f;
      const bool isp = val && (s > 0.0f);
      mloc = val ? fmaxf(mloc, s) : mloc;
      unsigned long long mp = __ballot(isp);
      if (isp)
        pseg[w][cp + lane_rank(mp)] =
            ((unsigned long long)(__float_as_uint(s) | 0x80000000u) << 32) | (unsigned)k;
      cp += (int)__popcll(mp);
      if (cz < 64) {                      // wave-uniform gate; stops once 64 banked
        const bool isz = val && (s == 0.0f);
        unsigned long long mz = __ballot(isz);
        if (isz) { const int o = cz + lane_rank(mz); if (o < 64) zseg[w][o] = k; }
        cz += (int)__popcll(mz);
      }
    }
#pragma unroll
    for (int off = 32; off; off >>= 1) mloc = fmaxf(mloc, __shfl_xor(mloc, off));
    const float m = mloc;
    const bool czfull = (cz >= 64);

    if (cp <= 64 && (czfull || cp + cz >= 64)) {
      // fast path: boundary is exactly +0 (or smallest positive when cp==64)
      if (lane < cp) {
        const unsigned long long kk = pseg[w][lane];
        const float p = __expf(__uint_as_float((unsigned)(kk >> 32) & 0x7fffffffu) - m);
        selpk[w][lane] = ((unsigned long long)__float_as_uint(p) << 32)
                       | (unsigned)(((unsigned)kk) << 10);
      }
      const int quota = 64 - cp;
      if (lane < quota)
        selpk[w][cp + lane] = ((unsigned long long)__float_as_uint(__expf(-m)) << 32)
                            | (unsigned)(zseg[w][lane] << 10);
      nsel = 64;
    } else if (cp > 64) {
      wave_radix_sel(pseg[w], cp, 64, hist[w], selpk[w], 0, false, m, lane);
      nsel = 64;
    } else {
      // rare: boundary dips into negatives (cp + cz < 64; cz exact here)
      if (lane < cp) {
        const unsigned long long kk = pseg[w][lane];
        const float p = __expf(__uint_as_float((unsigned)(kk >> 32) & 0x7fffffffu) - m);
        selpk[w][lane] = ((unsigned long long)__float_as_uint(p) << 32)
                       | (unsigned)(((unsigned)kk) << 10);
      }
      if (lane < cz)
        selpk[w][cp + lane] = ((unsigned long long)__float_as_uint(__expf(-m)) << 32)
                            | (unsigned)(zseg[w][lane] << 10);
      int cn = 0;
      for (int k0 = 0; k0 < nvalid; k0 += 64) {
        const int k = k0 + lane;
        const bool val = (k < nvalid);
        float s = (v0 * kr0[k] + v1 * kr1[k] + v2 * kr2[k] + v3 * kr3[k]) * 0.125f;
        const bool isn = val && (s < 0.0f);
        unsigned long long mn = __ballot(isn);
        if (isn)
          pseg[w][cn + lane_rank(mn)] =
              ((unsigned long long)mono_key(s) << 32) | (unsigned)k;
        cn += (int)__popcll(mn);
      }
      wave_radix_sel(pseg[w], cn, 64 - cp - cz, hist[w], selpk[w],
                     cp + cz, true, m, lane);
      nsel = 64;
    }
  }

  const unsigned long long eL = (lane < nsel) ? selpk[w][lane] : 0ull;
  float Zp = (lane < nsel) ? __uint_as_float((unsigned)(eL >> 32)) : 0.0f;
#pragma unroll
  for (int off = 32; off; off >>= 1) Zp += __shfl_xor(Zp, off);
  const float Z = Zp;

  // epilogue: vbh is wave-uniform; selpk low 32 = element offset k*1024
  float acc = 0.0f;
  const float* vbh = Vy + ((size_t)b * TSEQ) * 1024 + h * HD;
  int s2 = 0;
  for (; s2 + 4 <= nsel; s2 += 4) {
    const ulonglong2 ea = *(const ulonglong2*)&selpk[w][s2];
    const ulonglong2 eb = *(const ulonglong2*)&selpk[w][s2 + 2];
    acc += __uint_as_float((unsigned)(ea.x >> 32)) * vbh[(unsigned)ea.x + lane]
         + __uint_as_float((unsigned)(ea.y >> 32)) * vbh[(unsigned)ea.y + lane]
         + __uint_as_float((unsigned)(eb.x >> 32)) * vbh[(unsigned)eb.x + lane]
         + __uint_as_float((unsigned)(eb.y >> 32)) * vbh[(unsigned)eb.y + lane];
  }
  for (; s2 < nsel; ++s2) {
    const unsigned long long e = selpk[w][s2];
    acc += __uint_as_float((unsigned)(e >> 32)) * vbh[(unsigned)e + lane];
  }
  const float r = acc / Z;
  unsigned short rh, rm;
  split2(r, rh, rm);
  const size_t oidx = ((size_t)(b * TSEQ + q)) * 1024 + h * HD + lane;
  Oh[oidx] = rh;
  Om[oidx] = rm;
}

// ---------------- launch -----------------------------------------------------
extern "C" void kernel_launch(void* const* d_in, const int* in_sizes, int n_in,
                              void* d_out, int out_size, void* d_ws, size_t ws_size,
                              hipStream_t stream) {
  (void)in_sizes; (void)n_in; (void)out_size; (void)ws_size;
  const float* x  = (const float*)d_in[0];
  const float* wq = (const float*)d_in[1];
  const float* wk = (const float*)d_in[2];
  const float* wv = (const float*)d_in[3];
  const float* wo = (const float*)d_in[4];
  float* out = (float*)d_out;

  float* ws = (float*)d_ws;
  const size_t SZ = (size_t)4096 * 1024;   // 4M floats = 16MB per buffer
  float* qy  = ws;
  float* vy  = ws + 2 * SZ;
  float* kt  = ws + 3 * SZ;
  ushort_t* xs  = (ushort_t*)(ws + 4 * SZ);   // 8M ushorts (x hi|mid)
  ushort_t* wsb = (ushort_t*)(ws + 5 * SZ);   // 8M ushorts (4 x (hi|mid))
  ushort_t* oys = xs;                         // xs dead after mfma_qkv

  conv_split<<<8192, 256, 0, stream>>>(x, wq, wk, wv, wo, xs, wsb);

  // QKV GEMM + in-register top-4 sparsify + direct transposed K write
  mfma_qkv<<<dim3(24, 64), 256, 0, stream>>>(xs, wsb, qy, kt, vy);

  attn_sparse<<<dim3(TSEQ / 4, 64), 256, 0, stream>>>(qy, kt, vy,
                                                      oys, oys + (1u << 22));

  mfma_wo<<<dim3(8, 64), 256, 0, stream>>>(oys, wsb, out);
}

// Round 15
// 330.717 us; speedup vs baseline: 1.1701x; 1.1701x over previous
//
#include <hip/hip_runtime.h>
#include <math.h>

#define TSEQ 1024
#define NH 16
#define HD 64

typedef short bf16x8 __attribute__((ext_vector_type(8)));
typedef float f32x4  __attribute__((ext_vector_type(4)));
typedef unsigned short ushort_t;
typedef unsigned long long ull_t;

__device__ __forceinline__ int lane_rank(unsigned long long m) {
  return __builtin_amdgcn_mbcnt_hi((unsigned)(m >> 32),
         __builtin_amdgcn_mbcnt_lo((unsigned)m, 0u));
}

// async global->LDS, 16B per lane; LDS dest must be wave-uniform base + lane*16
__device__ __forceinline__ void async_ld16(const ushort_t* gsrc, ushort_t* ldst) {
  __builtin_amdgcn_global_load_lds(
      (const __attribute__((address_space(1))) unsigned int*)gsrc,
      (__attribute__((address_space(3))) unsigned int*)ldst,
      16, 0, 0);
}

// ---------------- fp32 -> (hi, mid) bf16 split --------------------------------
__device__ __forceinline__ unsigned short rne_bf16(float a) {
  unsigned u = __float_as_uint(a);
  return (unsigned short)((u + 0x7fffu + ((u >> 16) & 1u)) >> 16);
}
__device__ __forceinline__ void split2(float a, unsigned short& h, unsigned short& m) {
  h = rne_bf16(a);
  float hf = __uint_as_float(((unsigned)h) << 16);
  m = rne_bf16(a - hf);
}

// fused conversion of x (4M) + wq/wk/wv/wo (1M each) into split buffers
__global__ __launch_bounds__(256) void conv_split(
    const float* __restrict__ x,
    const float* __restrict__ wq, const float* __restrict__ wk,
    const float* __restrict__ wv, const float* __restrict__ wo,
    ushort_t* __restrict__ xs, ushort_t* __restrict__ wsb)
{
  const int e = (blockIdx.x * 256 + threadIdx.x) * 4;
  const float* src; ushort_t *hp, *mp; int off;
  if (e < (1 << 22)) {
    src = x; off = e; hp = xs; mp = xs + (1u << 22);
  } else {
    int j = e - (1 << 22);
    int mat = j >> 20; off = j & ((1 << 20) - 1);
    src = (mat == 0) ? wq : (mat == 1) ? wk : (mat == 2) ? wv : wo;
    hp = wsb + (size_t)mat * (2u << 20); mp = hp + (1u << 20);
  }
  float4 v = *(const float4*)(src + off);
  ushort4 h, m;
  split2(v.x, h.x, m.x); split2(v.y, h.y, m.y);
  split2(v.z, h.z, m.z); split2(v.w, h.w, m.w);
  *(ushort4*)(hp + off) = h;
  *(ushort4*)(mp + off) = m;
}

// ---------------- split-bf16 MFMA GEMM: C = A[M,K] * B[N,K]^T -----------------
// 3-term split: hh + hm + mh (mm dropped: |am*bm| ~ 1.6e-5 relative).
// Staging via global_load_lds width=16 (async DMA, no VGPR round-trip).
// 128x128 tile: measured optimum of this 2-barrier structure (64x128 at
// 6 blocks/CU doubled B re-fetch, 73->183MB, and regressed 107->183us).
// mode 0: dense C store (WO).
// mode 1: in-register top-4 |v| sparsify per (row,head)-vector, dense C store.
// mode 2: sparsify + store transposed into KT[bh][j][t] (K path).
__device__ __forceinline__ void mfma_gemm_core(
    const ushort_t* __restrict__ Ah, const ushort_t* __restrict__ Am,
    const ushort_t* __restrict__ Bh, const ushort_t* __restrict__ Bm,
    float* __restrict__ C, float* __restrict__ KTb,
    const int bm, const int bn, const int mode)
{
  __shared__ ushort_t ldsA[8192];   // [split][128][32]
  __shared__ ushort_t ldsB[8192];
  const int tid  = threadIdx.x;
  const int lane = tid & 63;
  const int w    = tid >> 6;
  const int wm = (w >> 1) << 6;
  const int wn = (w & 1) << 6;
  const int r16 = lane & 15;
  const int q   = lane >> 4;

  // per-lane global srcs; LDS dst = wave-uniform base + lane*16B (8 ushorts)
  const ushort_t* ga[4]; const ushort_t* gb[4]; int dst[4];
#pragma unroll
  for (int r = 0; r < 4; ++r) {
    const int linear = tid + 256 * r;
    const int s   = linear >> 9;
    const int idx = linear & 511;
    const int row = idx >> 2;
    const int kq  = (idx & 3) << 3;
    ga[r] = (s ? Am : Ah) + (size_t)(bm + row) * 1024 + kq;
    gb[r] = (s ? Bm : Bh) + (size_t)(bn + row) * 1024 + kq;
    dst[r] = linear << 3;
  }

  f32x4 acc[4][4];
#pragma unroll
  for (int mt = 0; mt < 4; ++mt)
#pragma unroll
    for (int nt = 0; nt < 4; ++nt) { f32x4 z = {0.f, 0.f, 0.f, 0.f}; acc[mt][nt] = z; }

  for (int k0 = 0; k0 < 1024; k0 += 32) {
    __syncthreads();                 // previous iter's LDS reads complete
#pragma unroll
    for (int r = 0; r < 4; ++r) {
      async_ld16(ga[r], &ldsA[dst[r]]);
      async_ld16(gb[r], &ldsB[dst[r]]);
      ga[r] += 32; gb[r] += 32;
    }
    __syncthreads();                 // implicit vmcnt(0) drains the DMA

    bf16x8 bf[4][2];
#pragma unroll
    for (int nt = 0; nt < 4; ++nt) {
      bf[nt][0] = *(const bf16x8*)&ldsB[(wn + nt * 16 + r16) * 32 + q * 8];
      bf[nt][1] = *(const bf16x8*)&ldsB[4096 + (wn + nt * 16 + r16) * 32 + q * 8];
    }
#pragma unroll
    for (int mt = 0; mt < 4; ++mt) {
      const bf16x8 ah = *(const bf16x8*)&ldsA[(wm + mt * 16 + r16) * 32 + q * 8];
      const bf16x8 am = *(const bf16x8*)&ldsA[4096 + (wm + mt * 16 + r16) * 32 + q * 8];
#pragma unroll
      for (int nt = 0; nt < 4; ++nt) {
        f32x4 c = acc[mt][nt];
        c = __builtin_amdgcn_mfma_f32_16x16x32_bf16(am, bf[nt][0], c, 0, 0, 0); // mh
        c = __builtin_amdgcn_mfma_f32_16x16x32_bf16(ah, bf[nt][1], c, 0, 0, 0); // hm
        c = __builtin_amdgcn_mfma_f32_16x16x32_bf16(ah, bf[nt][0], c, 0, 0, 0); // hh
        acc[mt][nt] = c;
      }
    }
  }

  if (mode != 0) {
    // in-register top-4 |v| sparsify: tie -> lowest j (matches jax top_k).
#pragma unroll
    for (int it = 0; it < 16; ++it) {
      const int mti = it >> 2, r4i = it & 3;
      int cons = 0;
#pragma unroll
      for (int rnd = 0; rnd < 4; ++rnd) {
        float bv = -1.0f; int bj = 1024;
#pragma unroll
        for (int nt = 0; nt < 4; ++nt) {
          const float av = ((cons >> nt) & 1) ? -1.0f : fabsf(acc[mti][nt][r4i]);
          const int jj = nt * 16 + r16;
          if (av > bv) { bv = av; bj = jj; }
        }
#pragma unroll
        for (int off = 1; off < 16; off <<= 1) {
          const float ov = __shfl_xor(bv, off);
          const int   oj = __shfl_xor(bj, off);
          if (ov > bv || (ov == bv && oj < bj)) { bv = ov; bj = oj; }
        }
        if ((bj & 15) == r16) cons |= 1 << (bj >> 4);
      }
#pragma unroll
      for (int nt = 0; nt < 4; ++nt)
        if (!((cons >> nt) & 1)) acc[mti][nt][r4i] = 0.0f;
    }
  }

  if (mode == 2) {
    // K path: store transposed into KT[bh][j][t]; acc regs are 4 consecutive t
    const int row0 = bm + wm;
    const int b = row0 >> 10;
    const int h = (bn + wn) >> 6;
    float* kb = KTb + ((size_t)(b * 16 + h) << 16);
    const int tb = (row0 & 1023) + q * 4;
#pragma unroll
    for (int mt = 0; mt < 4; ++mt) {
      const int t0 = tb + mt * 16;
#pragma unroll
      for (int nt = 0; nt < 4; ++nt) {
        const int j = nt * 16 + r16;
        *(float4*)(kb + (size_t)j * 1024 + t0) =
            make_float4(acc[mt][nt][0], acc[mt][nt][1], acc[mt][nt][2], acc[mt][nt][3]);
      }
    }
  } else {
#pragma unroll
    for (int mt = 0; mt < 4; ++mt)
#pragma unroll
      for (int nt = 0; nt < 4; ++nt)
#pragma unroll
        for (int r4 = 0; r4 < 4; ++r4)
          C[(size_t)(bm + wm + mt * 16 + q * 4 + r4) * 1024 + (bn + wn + nt * 16 + r16)] =
              acc[mt][nt][r4];
  }
}

// fused Q/K/V + sparsify + K-transpose: grid (24, 32)
__global__ __launch_bounds__(256, 3) void mfma_qkv(
    const ushort_t* __restrict__ xs, const ushort_t* __restrict__ wsb,
    float* __restrict__ qy, float* __restrict__ kt, float* __restrict__ vy)
{
  const int nb = blockIdx.x;
  const int which = nb >> 3;
  float* C = (which == 0) ? qy : vy;       // unused for K (mode 2)
  const int mode = (which == 1) ? 2 : 1;
  const ushort_t* Bh = wsb + (size_t)which * (2u << 20);
  mfma_gemm_core(xs, xs + (1u << 22), Bh, Bh + (1u << 20), C, kt,
                 blockIdx.y * 128, (nb & 7) * 128, mode);
}

__global__ __launch_bounds__(256, 3) void mfma_wo(
    const ushort_t* __restrict__ oys, const ushort_t* __restrict__ wsb,
    float* __restrict__ out)
{
  const ushort_t* Bh = wsb + (size_t)3 * (2u << 20);
  mfma_gemm_core(oys, oys + (1u << 22), Bh, Bh + (1u << 20), out, nullptr,
                 blockIdx.y * 128, blockIdx.x * 128, 0);
}

// ---------------- attention: wave-synchronous, one wave per q-row -----------
__device__ __forceinline__ unsigned mono_key(float f) {
  unsigned b = __float_as_uint(f);
  return (b & 0x80000000u) ? ~b : (b | 0x80000000u);
}

// Wave-local exact rank-select over index-ordered ps[0..cnt) (hi32 = mono
// score, lo32 = k). Selects hi32 > threshold plus first `rem` (array order)
// == threshold; writes packed (expf(s-m), k*1024) at obase into spk.
// Early exit when the boundary bin holds exactly `rem` keys.
__device__ __forceinline__ void wave_radix_sel(
    unsigned long long* ps, int cnt, int target,
    int* hr, unsigned long long* spk, int obase, bool neg, float m,
    int lane)
{
  unsigned pref = 0u; int rem = target; int sstop = 0;
  for (int pass = 0; pass < 4; ++pass) {
    const int shift = 24 - 8 * pass;
    sstop = shift;
    hr[lane] = 0; hr[lane + 64] = 0; hr[lane + 128] = 0; hr[lane + 192] = 0;
    for (int c0 = 0; c0 < cnt; c0 += 64) {
      const int t = c0 + lane;
      bool pt = (t < cnt);
      const unsigned u = pt ? (unsigned)(ps[t] >> 32) : 0u;
      if (pass > 0) pt = pt && ((u >> (shift + 8)) == (pref >> (shift + 8)));
      if (pt) atomicAdd(&hr[(u >> shift) & 255u], 1);
    }
    const int d0 = lane << 2;
    const int c0b = hr[d0], c1b = hr[d0 + 1], c2b = hr[d0 + 2], c3b = hr[d0 + 3];
    const int sum = c0b + c1b + c2b + c3b;
    int S = sum;
#pragma unroll
    for (int off = 1; off < 64; off <<= 1) {
      int t = __shfl_down(S, off);
      if (lane + off < 64) S += t;
    }
    const int above = S - sum;            // keys with digit in higher lanes
    const int cg3 = above;
    const int cg2 = above + c3b;
    const int cg1 = cg2 + c2b;
    const int cg0 = cg1 + c1b;
    const bool f0 = (cg0 < rem && rem <= cg0 + c0b);
    const bool f1 = (cg1 < rem && rem <= cg1 + c1b);
    const bool f2 = (cg2 < rem && rem <= cg2 + c2b);
    const bool f3 = (cg3 < rem && rem <= cg3 + c3b);
    const int fd  = f0 ? d0 : f1 ? (d0 + 1) : f2 ? (d0 + 2) : (d0 + 3);
    const int fcg = f0 ? cg0 : f1 ? cg1 : f2 ? cg2 : cg3;
    const int fcn = f0 ? c0b : f1 ? c1b : f2 ? c2b : c3b;
    unsigned long long fm = __ballot(f0 || f1 || f2 || f3);
    const int src = __ffsll(fm) - 1;
    const int nprefl = (int)(pref | ((unsigned)fd << shift));
    const int nreml = rem - fcg;
    const int done  = (fcn == nreml) ? 1 : 0;
    pref = (unsigned)__shfl(nprefl, src);
    rem  = __shfl(nreml, src);
    if (__shfl(done, src)) break;   // bin == rem: all members selected, exact
  }
  const unsigned phi = pref >> sstop;
  int eqbase = 0, wbase = 0;
  for (int c0 = 0; c0 < cnt; c0 += 64) {
    const int t = c0 + lane;
    const bool valt = (t < cnt);
    const unsigned long long kk = valt ? ps[t] : 0ull;
    const unsigned u = (unsigned)(kk >> 32);
    const unsigned upre = u >> sstop;
    const bool eq = valt && (upre == phi);
    unsigned long long em = __ballot(eq);
    const int eqrank = eqbase + lane_rank(em);
    const bool sf = valt && ((upre > phi) || (eq && eqrank < rem));
    unsigned long long sm = __ballot(sf);
    if (sf) {
      const int pos = wbase + lane_rank(sm);
      const float sv = neg ? __uint_as_float(~u) : __uint_as_float(u & 0x7fffffffu);
      spk[obase + pos] = ((unsigned long long)__float_as_uint(__expf(sv - m)) << 32)
                       | (unsigned)(((unsigned)kk) << 10);
    }
    eqbase += (int)__popcll(em);
    wbase  += (int)__popcll(sm);
  }
}

__global__ __launch_bounds__(256) void attn_sparse(
    const float* __restrict__ Qy, const float* __restrict__ KT,
    const float* __restrict__ Vy,
    ushort_t* __restrict__ Oh, ushort_t* __restrict__ Om)
{
  const int bh = blockIdx.y;
  const int b  = bh >> 4;
  const int h  = bh & 15;
  const int tid  = threadIdx.x;
  const int lane = tid & 63;
  const int w    = tid >> 6;
  const int bi   = blockIdx.x;
  // load-balanced row map: per-block total nvalid is constant (2050)
  const int q = (w == 0) ? bi : (w == 1) ? (511 - bi) : (w == 2) ? (512 + bi) : (1023 - bi);

  __shared__ unsigned long long pseg[4][256];
  __shared__ int   zseg[4][64];
  __shared__ unsigned long long selpk[4][64];   // packed (p:f32 hi | k*1024 lo)
  __shared__ int   hist[4][256];

  // q nonzeros: ffsll-peel the ballot mask, broadcast values via shfl
  const float qv = Qy[((size_t)(b * TSEQ + q)) * 1024 + h * HD + lane];
  unsigned long long mk = __ballot(qv != 0.0f);
  const int nnz = (int)__popcll(mk);
  unsigned long long mr = mk;
  int i0 = __ffsll(mr) - 1; if (i0 < 0) i0 = 0; mr &= mr - 1;
  int i1 = __ffsll(mr) - 1; if (i1 < 0) i1 = 0; mr &= mr - 1;
  int i2 = __ffsll(mr) - 1; if (i2 < 0) i2 = 0; mr &= mr - 1;
  int i3 = __ffsll(mr) - 1; if (i3 < 0) i3 = 0;
  float v0 = __shfl(qv, i0); if (nnz < 1) v0 = 0.0f;
  float v1 = __shfl(qv, i1); if (nnz < 2) v1 = 0.0f;
  float v2 = __shfl(qv, i2); if (nnz < 3) v2 = 0.0f;
  float v3 = __shfl(qv, i3); if (nnz < 4) v3 = 0.0f;
  const float* ktb = KT + (size_t)bh * HD * TSEQ;
  const float* kr0 = ktb + (size_t)i0 * TSEQ;
  const float* kr1 = ktb + (size_t)i1 * TSEQ;
  const float* kr2 = ktb + (size_t)i2 * TSEQ;
  const float* kr3 = ktb + (size_t)i3 * TSEQ;

  const int nvalid = q + 1;
  int nsel;

  if (nvalid <= 64) {
    const bool val = (lane < nvalid);
    float s = (v0 * kr0[lane] + v1 * kr1[lane] + v2 * kr2[lane] + v3 * kr3[lane]) * 0.125f;
    float mloc = val ? s : -INFINITY;
#pragma unroll
    for (int off = 32; off; off >>= 1) mloc = fmaxf(mloc, __shfl_xor(mloc, off));
    if (val)
      selpk[w][lane] = ((unsigned long long)__float_as_uint(__expf(s - mloc)) << 32)
                     | (unsigned)(lane << 10);
    nsel = nvalid;
  } else {
    int cp = 0, cz = 0;
    float mloc = -INFINITY;
#pragma unroll 2
    for (int k0 = 0; k0 < nvalid; k0 += 64) {
      const int k = k0 + lane;
      const bool val = (k < nvalid);
      // unguarded loads: worst-case 63 elements past row end stay inside d_ws
      float s = (v0 * kr0[k] + v1 * kr1[k] + v2 * kr2[k] + v3 * kr3[k]) * 0.125f;
      const bool isp = val && (s > 0.0f);
      mloc = val ? fmaxf(mloc, s) : mloc;
      unsigned long long mp = __ballot(isp);
      if (isp)
        pseg[w][cp + lane_rank(mp)] =
            ((unsigned long long)(__float_as_uint(s) | 0x80000000u) << 32) | (unsigned)k;
      cp += (int)__popcll(mp);
      if (cz < 64) {                      // wave-uniform gate; stops once 64 banked
        const bool isz = val && (s == 0.0f);
        unsigned long long mz = __ballot(isz);
        if (isz) { const int o = cz + lane_rank(mz); if (o < 64) zseg[w][o] = k; }
        cz += (int)__popcll(mz);
      }
    }
#pragma unroll
    for (int off = 32; off; off >>= 1) mloc = fmaxf(mloc, __shfl_xor(mloc, off));
    const float m = mloc;
    const bool czfull = (cz >= 64);

    if (cp <= 64 && (czfull || cp + cz >= 64)) {
      // fast path: boundary is exactly +0 (or smallest positive when cp==64)
      if (lane < cp) {
        const unsigned long long kk = pseg[w][lane];
        const float p = __expf(__uint_as_float((unsigned)(kk >> 32) & 0x7fffffffu) - m);
        selpk[w][lane] = ((unsigned long long)__float_as_uint(p) << 32)
                       | (unsigned)(((unsigned)kk) << 10);
      }
      const int quota = 64 - cp;
      if (lane < quota)
        selpk[w][cp + lane] = ((unsigned long long)__float_as_uint(__expf(-m)) << 32)
                            | (unsigned)(zseg[w][lane] << 10);
      nsel = 64;
    } else if (cp > 64) {
      wave_radix_sel(pseg[w], cp, 64, hist[w], selpk[w], 0, false, m, lane);
      nsel = 64;
    } else {
      // rare: boundary dips into negatives (cp + cz < 64; cz exact here)
      if (lane < cp) {
        const unsigned long long kk = pseg[w][lane];
        const float p = __expf(__uint_as_float((unsigned)(kk >> 32) & 0x7fffffffu) - m);
        selpk[w][lane] = ((unsigned long long)__float_as_uint(p) << 32)
                       | (unsigned)(((unsigned)kk) << 10);
      }
      if (lane < cz)
        selpk[w][cp + lane] = ((unsigned long long)__float_as_uint(__expf(-m)) << 32)
                            | (unsigned)(zseg[w][lane] << 10);
      int cn = 0;
      for (int k0 = 0; k0 < nvalid; k0 += 64) {
        const int k = k0 + lane;
        const bool val = (k < nvalid);
        float s = (v0 * kr0[k] + v1 * kr1[k] + v2 * kr2[k] + v3 * kr3[k]) * 0.125f;
        const bool isn = val && (s < 0.0f);
        unsigned long long mn = __ballot(isn);
        if (isn)
          pseg[w][cn + lane_rank(mn)] =
              ((unsigned long long)mono_key(s) << 32) | (unsigned)k;
        cn += (int)__popcll(mn);
      }
      wave_radix_sel(pseg[w], cn, 64 - cp - cz, hist[w], selpk[w],
                     cp + cz, true, m, lane);
      nsel = 64;
    }
  }

  const unsigned long long eL = (lane < nsel) ? selpk[w][lane] : 0ull;
  float Zp = (lane < nsel) ? __uint_as_float((unsigned)(eL >> 32)) : 0.0f;
#pragma unroll
  for (int off = 32; off; off >>= 1) Zp += __shfl_xor(Zp, off);
  const float Z = Zp;

  // epilogue: vbh is wave-uniform; selpk low 32 = element offset k*1024
  float acc = 0.0f;
  const float* vbh = Vy + ((size_t)b * TSEQ) * 1024 + h * HD;
  int s2 = 0;
  for (; s2 + 4 <= nsel; s2 += 4) {
    const ulonglong2 ea = *(const ulonglong2*)&selpk[w][s2];
    const ulonglong2 eb = *(const ulonglong2*)&selpk[w][s2 + 2];
    acc += __uint_as_float((unsigned)(ea.x >> 32)) * vbh[(unsigned)ea.x + lane]
         + __uint_as_float((unsigned)(ea.y >> 32)) * vbh[(unsigned)ea.y + lane]
         + __uint_as_float((unsigned)(eb.x >> 32)) * vbh[(unsigned)eb.x + lane]
         + __uint_as_float((unsigned)(eb.y >> 32)) * vbh[(unsigned)eb.y + lane];
  }
  for (; s2 < nsel; ++s2) {
    const unsigned long long e = selpk[w][s2];
    acc += __uint_as_float((unsigned)(e >> 32)) * vbh[(unsigned)e + lane];
  }
  const float r = acc / Z;
  unsigned short rh, rm;
  split2(r, rh, rm);
  const size_t oidx = ((size_t)(b * TSEQ + q)) * 1024 + h * HD + lane;
  Oh[oidx] = rh;
  Om[oidx] = rm;
}

// ---------------- launch -----------------------------------------------------
extern "C" void kernel_launch(void* const* d_in, const int* in_sizes, int n_in,
                              void* d_out, int out_size, void* d_ws, size_t ws_size,
                              hipStream_t stream) {
  (void)in_sizes; (void)n_in; (void)out_size; (void)ws_size;
  const float* x  = (const float*)d_in[0];
  const float* wq = (const float*)d_in[1];
  const float* wk = (const float*)d_in[2];
  const float* wv = (const float*)d_in[3];
  const float* wo = (const float*)d_in[4];
  float* out = (float*)d_out;

  float* ws = (float*)d_ws;
  const size_t SZ = (size_t)4096 * 1024;   // 4M floats = 16MB per buffer
  float* qy  = ws;
  float* vy  = ws + 2 * SZ;
  float* kt  = ws + 3 * SZ;
  ushort_t* xs  = (ushort_t*)(ws + 4 * SZ);   // 8M ushorts (x hi|mid)
  ushort_t* wsb = (ushort_t*)(ws + 5 * SZ);   // 8M ushorts (4 x (hi|mid))
  ushort_t* oys = xs;                         // xs dead after mfma_qkv

  conv_split<<<8192, 256, 0, stream>>>(x, wq, wk, wv, wo, xs, wsb);

  // QKV GEMM + in-register top-4 sparsify + direct transposed K write
  mfma_qkv<<<dim3(24, 32), 256, 0, stream>>>(xs, wsb, qy, kt, vy);

  attn_sparse<<<dim3(TSEQ / 4, 64), 256, 0, stream>>>(qy, kt, vy,
                                                      oys, oys + (1u << 22));

  mfma_wo<<<dim3(8, 32), 256, 0, stream>>>(oys, wsb, out);
}